// Round 3
// baseline (3338.655 us; speedup 1.0000x reference)
//
#include <hip/hip_runtime.h>
#include <math.h>

// 8-layer transformer, B=16, S=512, H=1024, HEADS=4, dh=256, V=8000.
// Round 4 (= round 3 resubmit + FFN/FC on pipelined GEMM):
// counted-vmcnt pipelined GEMM (BM128xBN256xBK32, 3-stage LDS ring,
// raw s_barrier + s_waitcnt vmcnt(12), setprio, XCD swizzle) for ALL big
// GEMMs. MFMA flash attention from round 2 kept unchanged.

typedef unsigned short u16;
typedef unsigned int u32;
typedef __attribute__((ext_vector_type(8))) short short8;
typedef __attribute__((ext_vector_type(4))) float f32x4;

__device__ __forceinline__ u16 f2bf(float f) {
    u32 u = __builtin_bit_cast(u32, f);
    u32 r = (u + 0x7FFFu + ((u >> 16) & 1u)) >> 16;
    return (u16)r;
}
__device__ __forceinline__ float bf2f(u16 u) {
    u32 v = ((u32)u) << 16;
    return __builtin_bit_cast(float, v);
}
__device__ __forceinline__ float4 unpack4(uint2 r) {
    float4 f;
    f.x = __builtin_bit_cast(float, r.x << 16);
    f.y = __builtin_bit_cast(float, r.x & 0xffff0000u);
    f.z = __builtin_bit_cast(float, r.y << 16);
    f.w = __builtin_bit_cast(float, r.y & 0xffff0000u);
    return f;
}

// async 16B/lane global->LDS; ldsbase must be wave-uniform (HW adds lane*16)
__device__ __forceinline__ void stage16(const void* g, void* ldsbase, int lane) {
#if __has_builtin(__builtin_amdgcn_global_load_lds)
    __builtin_amdgcn_global_load_lds(
        (const __attribute__((address_space(1))) u32*)g,
        (__attribute__((address_space(3))) u32*)ldsbase, 16, 0, 0);
#else
    *(short8*)((u16*)ldsbase + lane * 8) = *(const short8*)g;
#endif
}

// ---------------------------------------------------------------------------
// Pipelined bf16 NT GEMM: C[m,n] = sum_k A[m,k]*B[n,k] + bias[n]
// BM=128, BN=256, BK=32, 256 threads (4 waves, wave n-split), 3-stage ring.
// Counted vmcnt: 2 K-tiles of loads (12) stay in flight across barriers.
// flags: bit0 = bf16 out, bit1 = exact GELU, bit2 = QKV mode (cols>=2048 go
// transposed to VtOut [b][h][dh][s]). M%128==0, N%256==0, K%32==0, K>=96.
// ---------------------------------------------------------------------------
__global__ __launch_bounds__(256, 2) void gemm_v2(
    const u16* __restrict__ A, const u16* __restrict__ B,
    const float* __restrict__ bias, void* __restrict__ C,
    int M, int N, int K, int ldc, int Nstore, int flags,
    u16* __restrict__ VtOut)
{
    __shared__ u16 As[3][128 * 32];
    __shared__ u16 Bs[3][256 * 32];
    const int tid = threadIdx.x;
    const int w = tid >> 6, lane = tid & 63;
    // XCD-aware bijective block remap (nwg % 8 == 0 for all our grids)
    const int nwg = gridDim.x * gridDim.y;
    int bid = blockIdx.y * gridDim.x + blockIdx.x;
    if ((nwg & 7) == 0) bid = (bid & 7) * (nwg >> 3) + (bid >> 3);
    const int n0 = (bid % gridDim.x) * 256;
    const int m0 = (bid / gridDim.x) * 128;

    const int srow = lane >> 2;          // staging: row within 16-row group
    const int sslot = lane & 3;          // staging: chunk slot (16B)
#define SW(r) (((r) & 3) ^ (((r) >> 2) & 3))

    const u16* Abase = A + (size_t)m0 * K;
    const u16* Bbase = B + (size_t)n0 * K;

    auto stageA = [&](int buf, int kt) {
        const int k0 = kt * 32;
#pragma unroll
        for (int i = 0; i < 2; ++i) {
            const int rbase = w * 32 + i * 16;
            const int r = rbase + srow;
            const int g = sslot ^ SW(r);
            stage16(Abase + (size_t)r * K + k0 + g * 8, &As[buf][rbase * 32], lane);
        }
    };
    auto stageB = [&](int buf, int kt) {
        const int k0 = kt * 32;
#pragma unroll
        for (int i = 0; i < 4; ++i) {
            const int rbase = w * 64 + i * 16;
            const int r = rbase + srow;
            const int g = sslot ^ SW(r);
            stage16(Bbase + (size_t)r * K + k0 + g * 8, &Bs[buf][rbase * 32], lane);
        }
    };

    f32x4 acc[8][4];
#pragma unroll
    for (int i = 0; i < 8; ++i)
#pragma unroll
        for (int j = 0; j < 4; ++j) {
            acc[i][j][0] = 0.f; acc[i][j][1] = 0.f;
            acc[i][j][2] = 0.f; acc[i][j][3] = 0.f;
        }
    const int col = lane & 15, quad = lane >> 4;
    const int wn = w * 64;
    const int nt = K >> 5;

    // prologue: tiles 0 and 1 in flight (12 loads/wave)
    stageA(0, 0); stageB(0, 0);
    stageA(1, 1); stageB(1, 1);

    int buf = 0;
    for (int t = 0; t < nt; ++t) {
        // bar1: all waves done reading buf[(t+2)%3] (tile t-1) before overwrite
        __builtin_amdgcn_s_barrier();
        if (t + 2 < nt) {
            int b2 = buf + 2; if (b2 >= 3) b2 -= 3;
            stageA(b2, t + 2); stageB(b2, t + 2);
            // tile t complete; tiles t+1,t+2 (12 loads) stay in flight
            asm volatile("s_waitcnt vmcnt(12)" ::: "memory");
        } else if (t + 1 < nt) {
            asm volatile("s_waitcnt vmcnt(6)" ::: "memory");
        } else {
            asm volatile("s_waitcnt vmcnt(0)" ::: "memory");
        }
        // bar2: everyone's tile-t loads landed
        __builtin_amdgcn_s_barrier();
        __builtin_amdgcn_sched_barrier(0);

        short8 bf4[4], af4[4];
#pragma unroll
        for (int j = 0; j < 4; ++j) {
            const int r = wn + j * 16 + col;
            bf4[j] = *(const short8*)&Bs[buf][r * 32 + ((quad ^ SW(r)) * 8)];
        }
#pragma unroll
        for (int i = 0; i < 4; ++i) {
            const int r = i * 16 + col;
            af4[i] = *(const short8*)&As[buf][r * 32 + ((quad ^ SW(r)) * 8)];
        }
        __builtin_amdgcn_s_setprio(1);
#pragma unroll
        for (int i = 0; i < 4; ++i)
#pragma unroll
            for (int j = 0; j < 4; ++j)
                acc[i][j] = __builtin_amdgcn_mfma_f32_16x16x32_bf16(
                    af4[i], bf4[j], acc[i][j], 0, 0, 0);
        __builtin_amdgcn_s_setprio(0);
#pragma unroll
        for (int i = 0; i < 4; ++i) {
            const int r = (4 + i) * 16 + col;
            af4[i] = *(const short8*)&As[buf][r * 32 + ((quad ^ SW(r)) * 8)];
        }
        __builtin_amdgcn_s_setprio(1);
#pragma unroll
        for (int i = 0; i < 4; ++i)
#pragma unroll
            for (int j = 0; j < 4; ++j)
                acc[4 + i][j] = __builtin_amdgcn_mfma_f32_16x16x32_bf16(
                    af4[i], bf4[j], acc[4 + i][j], 0, 0, 0);
        __builtin_amdgcn_s_setprio(0);
        buf = buf + 1; if (buf >= 3) buf -= 3;
    }

    // epilogue: D[row=(lane>>4)*4+r][col=lane&15] per 16x16 tile
    const int do_bf = flags & 1, do_gelu = flags & 2, do_qkv = flags & 4;
#pragma unroll
    for (int i = 0; i < 8; ++i)
#pragma unroll
        for (int j = 0; j < 4; ++j) {
            const int gr0 = m0 + i * 16 + quad * 4;
            const int gc = n0 + wn + j * 16 + col;
            if (gc < Nstore) {
                const float bv = bias ? bias[gc] : 0.f;
                if (do_qkv && gc >= 2048) {
                    // V part: write transposed bf16 to VtOut[b][h][d][s]
                    const int d = gc - 2048;
                    const int bb = gr0 >> 9, s = gr0 & 511;
                    ushort4 ov;
                    ov.x = f2bf(acc[i][j][0] + bv);
                    ov.y = f2bf(acc[i][j][1] + bv);
                    ov.z = f2bf(acc[i][j][2] + bv);
                    ov.w = f2bf(acc[i][j][3] + bv);
                    *(ushort4*)(VtOut +
                        (((size_t)(bb * 4 + (d >> 8)) * 256 + (d & 255)) * 512 + s)) = ov;
                } else {
#pragma unroll
                    for (int r = 0; r < 4; ++r) {
                        float v = acc[i][j][r] + bv;
                        if (do_gelu) v = 0.5f * v * (1.f + erff(v * 0.7071067811865475f));
                        if (do_bf) ((u16*)C)[(size_t)(gr0 + r) * ldc + gc] = f2bf(v);
                        else       ((float*)C)[(size_t)(gr0 + r) * ldc + gc] = v;
                    }
                }
            }
        }
#undef SW
}

// ---------------------------------------------------------------------------
// MFMA flash attention. Grid (8 qtiles, 4 heads, 16 batch), 256 thr (4 waves).
// ---------------------------------------------------------------------------
__global__ __launch_bounds__(256, 2) void attn_mfma(
    const u16* __restrict__ QK, const u16* __restrict__ Vt,
    const int* __restrict__ lengths,
    float* __restrict__ O, float* __restrict__ atten)
{
    __shared__ u16 sK[64 * 256];      // K tile (prologue: Q tile), swizzled
    __shared__ u16 sV[256 * 64];      // Vt tile [d][k], swizzled
    __shared__ u16 sP[4][16 * 64];    // per-wave P (bf16), swizzled
    const int qt = blockIdx.x, h = blockIdx.y, b = blockIdx.z;
    const int q0 = qt * 64;
    const int t = threadIdx.x;
    const int w = t >> 6, lane = t & 63;
    const int row = lane & 15, quad = lane >> 4;

    {   // stage Q rows into sK (swizzled), hoist frags to regs
        const u16* qbase = QK + (size_t)(b * 512 + q0) * 2048 + h * 256;
        const int r2 = lane >> 5, c = lane & 31;
#pragma unroll
        for (int i = 0; i < 8; ++i) {
            const int rr = w * 16 + i * 2 + r2;
            stage16(qbase + (size_t)rr * 2048 + ((c ^ (rr & 7)) * 8),
                    &sK[(w * 16 + i * 2) * 256], lane);
        }
    }
    __syncthreads();
    short8 qf[8];
    {
        const int qr = w * 16 + row;
#pragma unroll
        for (int ds = 0; ds < 8; ++ds) {
            const int chunk = ds * 4 + quad;
            qf[ds] = *(const short8*)&sK[qr * 256 + ((chunk ^ (qr & 7)) * 8)];
        }
    }
    __syncthreads();   // all Q frag reads done before K overwrites sK

    float mrow[4], lrow[4];
#pragma unroll
    for (int j = 0; j < 4; ++j) { mrow[j] = -3.0e38f; lrow[j] = 0.f; }
    f32x4 oacc[16];
#pragma unroll
    for (int dt = 0; dt < 16; ++dt) {
        oacc[dt][0] = 0.f; oacc[dt][1] = 0.f; oacc[dt][2] = 0.f; oacc[dt][3] = 0.f;
    }

    const int nkt = qt + 1;
    for (int kt = 0; kt < nkt; ++kt) {
        const int k0 = kt * 64;
        {   // stage K rows k0..k0+63 and Vt rows 0..255 (cols k0..k0+63)
            const u16* kbase = QK + (size_t)(b * 512 + k0) * 2048 + 1024 + h * 256;
            const int r2 = lane >> 5, c = lane & 31;
#pragma unroll
            for (int i = 0; i < 8; ++i) {
                const int rr = w * 16 + i * 2 + r2;
                stage16(kbase + (size_t)rr * 2048 + ((c ^ (rr & 7)) * 8),
                        &sK[(w * 16 + i * 2) * 256], lane);
            }
            const u16* vbase = Vt + ((size_t)(b * 4 + h) * 256) * 512 + k0;
            const int vr = lane >> 3, vc = lane & 7;
#pragma unroll
            for (int i = 0; i < 8; ++i) {
                const int dd = w * 64 + i * 8 + vr;
                stage16(vbase + (size_t)dd * 512 + ((vc ^ (dd & 7)) * 8),
                        &sV[(w * 64 + i * 8) * 64], lane);
            }
        }
        __syncthreads();   // staging drained

        // ---- QK^T: S[16q x 64k] per wave ----
        f32x4 sacc[4];
#pragma unroll
        for (int kt4 = 0; kt4 < 4; ++kt4) {
            sacc[kt4][0] = 0.f; sacc[kt4][1] = 0.f;
            sacc[kt4][2] = 0.f; sacc[kt4][3] = 0.f;
        }
#pragma unroll
        for (int ds = 0; ds < 8; ++ds) {
            const int chunk = ds * 4 + quad;
#pragma unroll
            for (int kt4 = 0; kt4 < 4; ++kt4) {
                const int kr = kt4 * 16 + row;
                const short8 kf = *(const short8*)&sK[kr * 256 + ((chunk ^ (kr & 7)) * 8)];
                sacc[kt4] = __builtin_amdgcn_mfma_f32_16x16x32_bf16(
                    qf[ds], kf, sacc[kt4], 0, 0, 0);
            }
        }

        // ---- online softmax (rows q = w*16 + quad*4 + j, cols k = kt4*16+row)
        const int diag = (kt == qt);
        float sc[4][4];
#pragma unroll
        for (int kt4 = 0; kt4 < 4; ++kt4)
#pragma unroll
            for (int j = 0; j < 4; ++j) {
                float v = sacc[kt4][j] * 0.03125f;     // 1/sqrt(1024)
                if (diag && (kt4 * 16 + row > w * 16 + quad * 4 + j)) v = -3.0e38f;
                sc[kt4][j] = v;
            }
        float alpha[4];
#pragma unroll
        for (int j = 0; j < 4; ++j) {
            float lm = fmaxf(fmaxf(sc[0][j], sc[1][j]), fmaxf(sc[2][j], sc[3][j]));
            lm = fmaxf(lm, __shfl_xor(lm, 1));
            lm = fmaxf(lm, __shfl_xor(lm, 2));
            lm = fmaxf(lm, __shfl_xor(lm, 4));
            lm = fmaxf(lm, __shfl_xor(lm, 8));
            const float mnew = fmaxf(mrow[j], lm);
            alpha[j] = __expf(mrow[j] - mnew);
            float ps = 0.f;
#pragma unroll
            for (int kt4 = 0; kt4 < 4; ++kt4) {
                sc[kt4][j] = __expf(sc[kt4][j] - mnew);
                ps += sc[kt4][j];
            }
            ps += __shfl_xor(ps, 1);
            ps += __shfl_xor(ps, 2);
            ps += __shfl_xor(ps, 4);
            ps += __shfl_xor(ps, 8);
            lrow[j] = lrow[j] * alpha[j] + ps;
            mrow[j] = mnew;
        }
        // P -> bf16 wave-private LDS (swizzled rows)
#pragma unroll
        for (int kt4 = 0; kt4 < 4; ++kt4)
#pragma unroll
            for (int j = 0; j < 4; ++j) {
                const int ql = quad * 4 + j;
                const int k = kt4 * 16 + row;
                sP[w][ql * 64 + (((k >> 3) ^ (ql & 7)) * 8) + (k & 7)] = f2bf(sc[kt4][j]);
            }
        // rescale O accumulators
#pragma unroll
        for (int dt = 0; dt < 16; ++dt) {
            oacc[dt][0] *= alpha[0]; oacc[dt][1] *= alpha[1];
            oacc[dt][2] *= alpha[2]; oacc[dt][3] *= alpha[3];
        }
        // ---- PV: O[16q x 256d] += P[16q x 64k] * Vt[256d x 64k]^T ----
#pragma unroll
        for (int kk = 0; kk < 2; ++kk) {
            const int chunk = kk * 4 + quad;
            const short8 pf = *(const short8*)&sP[w][row * 64 + ((chunk ^ (row & 7)) * 8)];
#pragma unroll
            for (int dt = 0; dt < 16; ++dt) {
                const int dr = dt * 16 + row;
                const short8 vf = *(const short8*)&sV[dr * 64 + ((chunk ^ (dr & 7)) * 8)];
                oacc[dt] = __builtin_amdgcn_mfma_f32_16x16x32_bf16(
                    pf, vf, oacc[dt], 0, 0, 0);
            }
        }
        __syncthreads();   // LDS reads done before next-tile staging
    }

    // ---- epilogue: faithful [B,HEADS,S,dh] flat order, zero invalid rows
    const int len = lengths[b];
#pragma unroll
    for (int j = 0; j < 4; ++j) {
        const int qg = q0 + w * 16 + quad * 4 + j;
        const float linv = (qg < len) ? 1.f / lrow[j] : 0.f;
        float* op = O + ((size_t)((b * 4 + h) * 512 + qg)) * 256;
#pragma unroll
        for (int dt = 0; dt < 16; ++dt)
            op[dt * 16 + row] = oacc[dt][j] * linv;
        if (atten && row == 0)
            atten[(size_t)(b * 4 + h) * 512 + qg] = linv;   // max_k p = 1/l
    }
}

// ---------------------------------------------------------------------------
// Embedding + sinusoidal PE, dual fp32/bf16 output
// ---------------------------------------------------------------------------
__global__ __launch_bounds__(256) void embed_kernel(
    const int* __restrict__ x, const float* __restrict__ emb,
    float* __restrict__ Z, u16* __restrict__ Zb)
{
    const int tokidx = blockIdx.x;
    const int s = tokidx & 511;
    const int t = threadIdx.x;
    const int tok = x[tokidx];
    const int c0 = t << 2;
    float4 e = *(const float4*)(emb + (size_t)tok * 1024 + c0);
    float pe[4];
#pragma unroll
    for (int j = 0; j < 4; ++j) {
        int c = c0 + j;
        float freq = expf((float)(c & ~1) * (-9.210340371976184f / 1024.f));
        float arg = (float)s * freq;
        pe[j] = (c & 1) ? cosf(arg) : sinf(arg);
    }
    float4 o = make_float4(e.x + pe[0], e.y + pe[1], e.z + pe[2], e.w + pe[3]);
    *(float4*)(Z + (size_t)tokidx * 1024 + c0) = o;
    ushort4 ob = {f2bf(o.x), f2bf(o.y), f2bf(o.z), f2bf(o.w)};
    ((ushort4*)(Zb + (size_t)tokidx * 1024))[t] = ob;
}

// ---------------------------------------------------------------------------
// Y = LayerNorm(X + R) * g + be, dual fp32/bf16 output (H = 1024)
// ---------------------------------------------------------------------------
__global__ __launch_bounds__(256) void add_ln(
    const float* __restrict__ X, const float* __restrict__ R,
    const float* __restrict__ g, const float* __restrict__ be,
    float* __restrict__ Y, u16* __restrict__ Yb)
{
    __shared__ float red[8];
    const int row = blockIdx.x;
    const int t = threadIdx.x;
    const float4 x = ((const float4*)(X + (size_t)row * 1024))[t];
    const float4 r = ((const float4*)(R + (size_t)row * 1024))[t];
    float v[4] = {x.x + r.x, x.y + r.y, x.z + r.z, x.w + r.w};
    float s = v[0] + v[1] + v[2] + v[3];
#pragma unroll
    for (int off = 32; off; off >>= 1) s += __shfl_xor(s, off);
    const int wid = t >> 6;
    if ((t & 63) == 0) red[wid] = s;
    __syncthreads();
    s = red[0] + red[1] + red[2] + red[3];
    const float mean = s * (1.f / 1024.f);
    float q = 0.f;
#pragma unroll
    for (int j = 0; j < 4; ++j) { float d = v[j] - mean; q += d * d; }
#pragma unroll
    for (int off = 32; off; off >>= 1) q += __shfl_xor(q, off);
    if ((t & 63) == 0) red[4 + wid] = q;
    __syncthreads();
    q = red[4] + red[5] + red[6] + red[7];
    const float rstd = rsqrtf(q * (1.f / 1024.f) + 1e-5f);
    const float4 gv = ((const float4*)g)[t];
    const float4 bv = ((const float4*)be)[t];
    float4 o;
    o.x = (v[0] - mean) * rstd * gv.x + bv.x;
    o.y = (v[1] - mean) * rstd * gv.y + bv.y;
    o.z = (v[2] - mean) * rstd * gv.z + bv.z;
    o.w = (v[3] - mean) * rstd * gv.w + bv.w;
    ((float4*)(Y + (size_t)row * 1024))[t] = o;
    ushort4 ob = {f2bf(o.x), f2bf(o.y), f2bf(o.z), f2bf(o.w)};
    ((ushort4*)(Yb + (size_t)row * 1024))[t] = ob;
}

// ---------------------------------------------------------------------------
// In-place row softmax over V=8000
// ---------------------------------------------------------------------------
__global__ __launch_bounds__(256) void softmax8000(float* __restrict__ P)
{
    __shared__ float red[8];
    float* p = P + (size_t)blockIdx.x * 8000;
    const int t = threadIdx.x;
    float vals[32];
    float mx = -3.0e38f;
#pragma unroll
    for (int j = 0; j < 32; ++j) {
        int c = t + (j << 8);
        if (c < 8000) { vals[j] = p[c]; mx = fmaxf(mx, vals[j]); }
    }
#pragma unroll
    for (int off = 32; off; off >>= 1) mx = fmaxf(mx, __shfl_xor(mx, off));
    const int wid = t >> 6;
    if ((t & 63) == 0) red[wid] = mx;
    __syncthreads();
    mx = fmaxf(fmaxf(red[0], red[1]), fmaxf(red[2], red[3]));
    float sum = 0.f;
#pragma unroll
    for (int j = 0; j < 32; ++j) {
        int c = t + (j << 8);
        if (c < 8000) { vals[j] = expf(vals[j] - mx); sum += vals[j]; }
    }
#pragma unroll
    for (int off = 32; off; off >>= 1) sum += __shfl_xor(sum, off);
    if ((t & 63) == 0) red[4 + wid] = sum;
    __syncthreads();
    const float inv = 1.f / (red[4] + red[5] + red[6] + red[7]);
#pragma unroll
    for (int j = 0; j < 32; ++j) {
        int c = t + (j << 8);
        if (c < 8000) p[c] = vals[j] * inv;
    }
}

// ---------------------------------------------------------------------------
// Weight / embedding conversion kernels (fp32 -> bf16), run each call
// ---------------------------------------------------------------------------
__global__ __launch_bounds__(256) void cvt_qkv(
    const float* __restrict__ Wq, const float* __restrict__ Wk,
    const float* __restrict__ Wv, u16* __restrict__ dst)
{
    const int n = blockIdx.x, l = blockIdx.y, t = threadIdx.x;
    const float* src = (n < 1024) ? Wq + ((size_t)l * 1024 + n) * 1024
                     : (n < 2048) ? Wk + ((size_t)l * 1024 + (n - 1024)) * 1024
                                  : Wv + ((size_t)l * 1024 + (n - 2048)) * 1024;
    float4 v = ((const float4*)src)[t];
    ushort4 o = {f2bf(v.x), f2bf(v.y), f2bf(v.z), f2bf(v.w)};
    ((ushort4*)(dst + ((size_t)l * 3072 + n) * 1024))[t] = o;
}

__global__ __launch_bounds__(256) void cvt_bias_qkv(
    const float* __restrict__ bq, const float* __restrict__ bk,
    const float* __restrict__ bv, float* __restrict__ dst)
{
    const int i = blockIdx.x * 256 + threadIdx.x;
    if (i >= 8 * 3072) return;
    const int l = i / 3072, n = i - l * 3072;
    float v = (n < 1024) ? bq[l * 1024 + n]
            : (n < 2048) ? bk[l * 1024 + (n - 1024)]
                         : bv[l * 1024 + (n - 2048)];
    dst[i] = v;
}

__global__ __launch_bounds__(256) void cvt_plain(
    const float* __restrict__ src, u16* __restrict__ dst, int n)
{
    const int i = (blockIdx.x * 256 + threadIdx.x) * 4;
    if (i >= n) return;
    float4 v = *(const float4*)(src + i);
    ushort4 o = {f2bf(v.x), f2bf(v.y), f2bf(v.z), f2bf(v.w)};
    *(ushort4*)(dst + i) = o;
}

__global__ __launch_bounds__(256) void cvt_emb(
    const float* __restrict__ emb, u16* __restrict__ dst)
{
    const int r = blockIdx.x, t = threadIdx.x;   // 8192 rows (pad to tile)
    ushort4 o = {0, 0, 0, 0};
    if (r < 8000) {
        float4 v = ((const float4*)(emb + (size_t)r * 1024))[t];
        o.x = f2bf(v.x); o.y = f2bf(v.y); o.z = f2bf(v.z); o.w = f2bf(v.w);
    }
    ((ushort4*)(dst + (size_t)r * 1024))[t] = o;
}

// ---------------------------------------------------------------------------
extern "C" void kernel_launch(void* const* d_in, const int* in_sizes, int n_in,
                              void* d_out, int out_size, void* d_ws, size_t ws_size,
                              hipStream_t stream)
{
    (void)in_sizes; (void)n_in; (void)out_size;
    const int*   x       = (const int*)d_in[0];
    const int*   lengths = (const int*)d_in[1];
    const float* emb = (const float*)d_in[2];
    const float* Wq  = (const float*)d_in[3];
    const float* bq  = (const float*)d_in[4];
    const float* Wk  = (const float*)d_in[5];
    const float* bk  = (const float*)d_in[6];
    const float* Wv  = (const float*)d_in[7];
    const float* bv  = (const float*)d_in[8];
    const float* W1  = (const float*)d_in[9];
    const float* b1  = (const float*)d_in[10];
    const float* W2  = (const float*)d_in[11];
    const float* b2  = (const float*)d_in[12];
    const float* g1  = (const float*)d_in[13];
    const float* be1 = (const float*)d_in[14];
    const float* g2  = (const float*)d_in[15];
    const float* be2 = (const float*)d_in[16];
    const float* Wfc = (const float*)d_in[17];
    const float* bfc = (const float*)d_in[18];

    float* out = (float*)d_out;
    float* atten = out + (size_t)65536000;

    // ---- buffer sizes (bytes, all 256-aligned already) ----
    const size_t SZ_EMBB = (size_t)8192 * 1024 * 2;   // padded emb bf16 (8192 rows)
    const size_t SZ_FCB  = (size_t)8192 * 1024 * 2;   // out_fc bf16 (survives to logits)
    const size_t SZ_BQKV = (size_t)8 * 3072 * 4;
    const size_t SZ_WQKV = (size_t)8 * 3072 * 1024 * 2;
    const size_t SZ_W12  = (size_t)8 * 1024 * 1024 * 2;
    const size_t SZ_WFC  = (size_t)1024 * 1024 * 2;
    const size_t SZ_Z    = (size_t)8192 * 1024 * 4;
    const size_t SZ_ZB   = (size_t)8192 * 1024 * 2;
    const size_t SZ_QKB  = (size_t)8192 * 2048 * 2;   // Q,K only
    const size_t SZ_VT   = (size_t)16 * 4 * 256 * 512 * 2;  // V transposed
    const size_t NONFORCED = SZ_WQKV + 2 * SZ_W12 + SZ_WFC + 2 * SZ_Z + SZ_ZB
                           + SZ_QKB + SZ_VT + SZ_Z;
    const size_t FORCED = SZ_EMBB + SZ_FCB + SZ_BQKV;
    const size_t GRAND = FORCED + NONFORCED;

    char* wsc = (char*)d_ws;
    char* oc  = (char*)d_out;
    const size_t ocap = (size_t)65536000 * 4;   // y_prim region: dead until logits GEMM
    size_t wo = 0, oo = 0;
    const bool all_ws = ws_size >= GRAND;
    // forced-to-ws (must survive while logits GEMM overwrites d_out):
    u16*   emb_bf = (u16*)(wsc + wo);  wo += SZ_EMBB;
    u16*   fc_b   = (u16*)(wsc + wo);  wo += SZ_FCB;
    float* bqkv   = (float*)(wsc + wo); wo += SZ_BQKV;
    auto alloc = [&](size_t sz) -> char* {
        if (all_ws) { char* p = wsc + wo; wo += sz; return p; }
        if (oo + sz <= ocap) { char* p = oc + oo; oo += sz; return p; }
        char* p = wsc + wo; wo += sz; return p;
    };
    u16*   Wqkv_bf = (u16*)alloc(SZ_WQKV);
    u16*   W1b     = (u16*)alloc(SZ_W12);
    u16*   W2b     = (u16*)alloc(SZ_W12);
    u16*   Wfcb    = (u16*)alloc(SZ_WFC);
    float* z       = (float*)alloc(SZ_Z);
    float* z1      = (float*)alloc(SZ_Z);
    u16*   zb      = (u16*)alloc(SZ_ZB);
    u16*   qkb     = (u16*)alloc(SZ_QKB);
    u16*   vtb     = (u16*)alloc(SZ_VT);
    float* o       = (float*)alloc(SZ_Z);
    // aliases inside qkb (attention finishes before these are written):
    u16* z1b = qkb;                             // [8192][1024] bf16
    u16* f1b = qkb + (size_t)8192 * 1024;       // [8192][1024] bf16

    dim3 blk(256);
    // weight / emb conversion (reads pristine fp32 inputs every call)
    cvt_qkv<<<dim3(3072, 8), blk, 0, stream>>>(Wq, Wk, Wv, Wqkv_bf);
    cvt_bias_qkv<<<96, blk, 0, stream>>>(bq, bk, bv, bqkv);
    cvt_plain<<<8192, blk, 0, stream>>>(W1, W1b, 8 * 1024 * 1024);
    cvt_plain<<<8192, blk, 0, stream>>>(W2, W2b, 8 * 1024 * 1024);
    cvt_plain<<<1024, blk, 0, stream>>>(Wfc, Wfcb, 1024 * 1024);
    cvt_emb<<<8192, blk, 0, stream>>>(emb, emb_bf);

    embed_kernel<<<8192, blk, 0, stream>>>(x, emb, z, zb);

    for (int l = 0; l < 8; ++l) {
        const size_t WO1 = (size_t)l * 1024 * 1024;
        const size_t BO = (size_t)l * 1024;
        // fused QKV GEMM (pipelined): Q,K bf16 -> qkb (ldc 2048), V^T -> vtb
        gemm_v2<<<dim3(12, 64), blk, 0, stream>>>(
            zb, Wqkv_bf + (size_t)l * 3072 * 1024, bqkv + (size_t)l * 3072,
            qkb, 8192, 3072, 1024, 2048, 3072, 1 | 4, vtb);
        attn_mfma<<<dim3(8, 4, 16), blk, 0, stream>>>(
            qkb, vtb, lengths, o, (l == 7) ? atten : nullptr);
        add_ln<<<8192, blk, 0, stream>>>(z, o, g1 + BO, be1 + BO, z1, z1b);
        gemm_v2<<<dim3(4, 64), blk, 0, stream>>>(
            z1b, W1b + WO1, b1 + BO, f1b, 8192, 1024, 1024, 1024, 1024, 1 | 2, nullptr);
        gemm_v2<<<dim3(4, 64), blk, 0, stream>>>(
            f1b, W2b + WO1, b2 + BO, o, 8192, 1024, 1024, 1024, 1024, 0, nullptr);
        add_ln<<<8192, blk, 0, stream>>>(z1, o, g2 + BO, be2 + BO, z, zb);
    }
    gemm_v2<<<dim3(4, 64), blk, 0, stream>>>(
        zb, Wfcb, bfc, fc_b, 8192, 1024, 1024, 1024, 1024, 1, nullptr);
    // logits GEMM (pipelined, emb padded to 8192 rows)
    gemm_v2<<<dim3(32, 64), blk, 0, stream>>>(
        fc_b, emb_bf, nullptr, out, 8192, 8192, 1024, 8000, 8000, 0, nullptr);
    softmax8000<<<8192, blk, 0, stream>>>(out);
}

// Round 4
// 2759.132 us; speedup vs baseline: 1.2100x; 1.2100x over previous
//
#include <hip/hip_runtime.h>
#include <math.h>

// 8-layer transformer, B=16, S=512, H=1024, HEADS=4, dh=256, V=8000.
// Round 5: gemm_p = proven 128x128/BK64 zero-conflict layout + 2-stage LDS
// ring with counted vmcnt(8) across raw barriers + setprio + XCD swizzle.
// Used for ALL GEMMs. MFMA flash attention unchanged (round 2).

typedef unsigned short u16;
typedef unsigned int u32;
typedef __attribute__((ext_vector_type(8))) short short8;
typedef __attribute__((ext_vector_type(4))) float f32x4;

__device__ __forceinline__ u16 f2bf(float f) {
    u32 u = __builtin_bit_cast(u32, f);
    u32 r = (u + 0x7FFFu + ((u >> 16) & 1u)) >> 16;
    return (u16)r;
}
__device__ __forceinline__ float bf2f(u16 u) {
    u32 v = ((u32)u) << 16;
    return __builtin_bit_cast(float, v);
}
__device__ __forceinline__ float4 unpack4(uint2 r) {
    float4 f;
    f.x = __builtin_bit_cast(float, r.x << 16);
    f.y = __builtin_bit_cast(float, r.x & 0xffff0000u);
    f.z = __builtin_bit_cast(float, r.y << 16);
    f.w = __builtin_bit_cast(float, r.y & 0xffff0000u);
    return f;
}

// async 16B/lane global->LDS; ldsbase must be wave-uniform (HW adds lane*16)
__device__ __forceinline__ void stage16(const void* g, void* ldsbase, int lane) {
#if __has_builtin(__builtin_amdgcn_global_load_lds)
    __builtin_amdgcn_global_load_lds(
        (const __attribute__((address_space(1))) u32*)g,
        (__attribute__((address_space(3))) u32*)ldsbase, 16, 0, 0);
#else
    *(short8*)((u16*)ldsbase + lane * 8) = *(const short8*)g;
#endif
}

// ---------------------------------------------------------------------------
// Pipelined bf16 NT GEMM: C[m,n] = sum_k A[m,k]*B[n,k] + bias[n]
// 128x128 tile, BK=64, 4 waves (2x2), 2-stage LDS ring (64 KB, 2 blocks/CU).
// Tile t+1's 8 global_load_lds stay in flight across both barriers
// (s_waitcnt vmcnt(8)); drain to 0 only on the last tile. LDS layout is the
// proven zero-conflict 128B-row XOR-chunk swizzle.
// flags: bit0 = bf16 out, bit1 = exact GELU, bit2 = QKV mode (cols>=2048 go
// transposed to VtOut [b][h][dh][s]). M%128==0, N%128==0, K%64==0.
// ---------------------------------------------------------------------------
__global__ __launch_bounds__(256, 2) void gemm_p(
    const u16* __restrict__ A, const u16* __restrict__ B,
    const float* __restrict__ bias, void* __restrict__ C,
    int M, int N, int K, int ldc, int Nstore, int flags,
    u16* __restrict__ VtOut)
{
    __shared__ u16 As[2][128 * 64];
    __shared__ u16 Bs[2][128 * 64];
    const int tid = threadIdx.x;
    const int w = tid >> 6, lane = tid & 63;
    // XCD-aware block remap (contiguous chunk per XCD); all grids are %8==0
    const int nwg = gridDim.x * gridDim.y;
    int bid = blockIdx.y * gridDim.x + blockIdx.x;
    if ((nwg & 7) == 0) bid = (bid & 7) * (nwg >> 3) + (bid >> 3);
    const int n0 = (bid % gridDim.x) * 128;
    const int m0 = (bid / gridDim.x) * 128;

    const int lr = lane >> 3;      // staging row-in-group (0..7)
    const int lc = lane & 7;       // staging chunk slot (16B)

    auto stages = [&](int buf, int kt) {
        const int k0 = kt * 64;
#pragma unroll
        for (int i = 0; i < 4; ++i) {
            const int ra = (w * 4 + i) * 8 + lr;         // tile row 0..127
            const int ca = lc ^ (ra & 7);                // swizzled global chunk
            stage16(A + (size_t)(m0 + ra) * K + k0 + ca * 8,
                    &As[buf][(w * 4 + i) * 512], lane);
            stage16(B + (size_t)(n0 + ra) * K + k0 + ca * 8,
                    &Bs[buf][(w * 4 + i) * 512], lane);
        }
    };

    f32x4 acc[4][4];
#pragma unroll
    for (int i = 0; i < 4; ++i)
#pragma unroll
        for (int j = 0; j < 4; ++j) {
            acc[i][j][0] = 0.f; acc[i][j][1] = 0.f;
            acc[i][j][2] = 0.f; acc[i][j][3] = 0.f;
        }
    const int row = lane & 15, quad = lane >> 4;
    const int wm = (w >> 1) * 64, wn = (w & 1) * 64;
    const int nt = K >> 6;

    // prologue: tiles 0,1 in flight (8 loads each per wave)
    stages(0, 0);
    if (nt > 1) stages(1, 1);

    for (int t = 0; t < nt; ++t) {
        // certify tile t landed; keep tile t+1's 8 loads in flight
        if (t + 1 < nt) asm volatile("s_waitcnt vmcnt(8)" ::: "memory");
        else            asm volatile("s_waitcnt vmcnt(0)" ::: "memory");
        __builtin_amdgcn_s_barrier();          // collective: tile t ready
        __builtin_amdgcn_sched_barrier(0);
        const int buf = t & 1;
#pragma unroll
        for (int kk = 0; kk < 2; ++kk) {
            const int g0 = kk * 4 + quad;      // global 8-elem chunk index
            short8 af[4], bfr[4];
#pragma unroll
            for (int i = 0; i < 4; ++i) {
                const int r = wm + i * 16 + row;
                af[i] = *(const short8*)&As[buf][r * 64 + ((g0 ^ (r & 7)) * 8)];
            }
#pragma unroll
            for (int j = 0; j < 4; ++j) {
                const int r = wn + j * 16 + row;
                bfr[j] = *(const short8*)&Bs[buf][r * 64 + ((g0 ^ (r & 7)) * 8)];
            }
            __builtin_amdgcn_s_setprio(1);
#pragma unroll
            for (int i = 0; i < 4; ++i)
#pragma unroll
                for (int j = 0; j < 4; ++j)
                    acc[i][j] = __builtin_amdgcn_mfma_f32_16x16x32_bf16(
                        af[i], bfr[j], acc[i][j], 0, 0, 0);
            __builtin_amdgcn_s_setprio(0);
        }
        __builtin_amdgcn_sched_barrier(0);
        __builtin_amdgcn_s_barrier();          // all waves done reading buf
        if (t + 2 < nt) stages(buf, t + 2);    // restage into freed buffer
    }

    // epilogue: D[row=(lane>>4)*4+r][col=lane&15] per 16x16 tile
    const int do_bf = flags & 1, do_gelu = flags & 2, do_qkv = flags & 4;
#pragma unroll
    for (int i = 0; i < 4; ++i)
#pragma unroll
        for (int j = 0; j < 4; ++j) {
            const int gr0 = m0 + wm + i * 16 + quad * 4;
            const int gc = n0 + wn + j * 16 + row;
            if (gc < Nstore) {
                const float bv = bias ? bias[gc] : 0.f;
                if (do_qkv && gc >= 2048) {
                    // V part: write transposed bf16 to VtOut[b][h][d][s]
                    const int d = gc - 2048;
                    const int bb = gr0 >> 9, s = gr0 & 511;
                    ushort4 ov;
                    ov.x = f2bf(acc[i][j][0] + bv);
                    ov.y = f2bf(acc[i][j][1] + bv);
                    ov.z = f2bf(acc[i][j][2] + bv);
                    ov.w = f2bf(acc[i][j][3] + bv);
                    *(ushort4*)(VtOut +
                        (((size_t)(bb * 4 + (d >> 8)) * 256 + (d & 255)) * 512 + s)) = ov;
                } else {
#pragma unroll
                    for (int r = 0; r < 4; ++r) {
                        float v = acc[i][j][r] + bv;
                        if (do_gelu) v = 0.5f * v * (1.f + erff(v * 0.7071067811865475f));
                        if (do_bf) ((u16*)C)[(size_t)(gr0 + r) * ldc + gc] = f2bf(v);
                        else       ((float*)C)[(size_t)(gr0 + r) * ldc + gc] = v;
                    }
                }
            }
        }
}

// ---------------------------------------------------------------------------
// MFMA flash attention. Grid (8 qtiles, 4 heads, 16 batch), 256 thr (4 waves).
// ---------------------------------------------------------------------------
__global__ __launch_bounds__(256, 2) void attn_mfma(
    const u16* __restrict__ QK, const u16* __restrict__ Vt,
    const int* __restrict__ lengths,
    float* __restrict__ O, float* __restrict__ atten)
{
    __shared__ u16 sK[64 * 256];      // K tile (prologue: Q tile), swizzled
    __shared__ u16 sV[256 * 64];      // Vt tile [d][k], swizzled
    __shared__ u16 sP[4][16 * 64];    // per-wave P (bf16), swizzled
    const int qt = blockIdx.x, h = blockIdx.y, b = blockIdx.z;
    const int q0 = qt * 64;
    const int t = threadIdx.x;
    const int w = t >> 6, lane = t & 63;
    const int row = lane & 15, quad = lane >> 4;

    {   // stage Q rows into sK (swizzled), hoist frags to regs
        const u16* qbase = QK + (size_t)(b * 512 + q0) * 2048 + h * 256;
        const int r2 = lane >> 5, c = lane & 31;
#pragma unroll
        for (int i = 0; i < 8; ++i) {
            const int rr = w * 16 + i * 2 + r2;
            stage16(qbase + (size_t)rr * 2048 + ((c ^ (rr & 7)) * 8),
                    &sK[(w * 16 + i * 2) * 256], lane);
        }
    }
    __syncthreads();
    short8 qf[8];
    {
        const int qr = w * 16 + row;
#pragma unroll
        for (int ds = 0; ds < 8; ++ds) {
            const int chunk = ds * 4 + quad;
            qf[ds] = *(const short8*)&sK[qr * 256 + ((chunk ^ (qr & 7)) * 8)];
        }
    }
    __syncthreads();   // all Q frag reads done before K overwrites sK

    float mrow[4], lrow[4];
#pragma unroll
    for (int j = 0; j < 4; ++j) { mrow[j] = -3.0e38f; lrow[j] = 0.f; }
    f32x4 oacc[16];
#pragma unroll
    for (int dt = 0; dt < 16; ++dt) {
        oacc[dt][0] = 0.f; oacc[dt][1] = 0.f; oacc[dt][2] = 0.f; oacc[dt][3] = 0.f;
    }

    const int nkt = qt + 1;
    for (int kt = 0; kt < nkt; ++kt) {
        const int k0 = kt * 64;
        {   // stage K rows k0..k0+63 and Vt rows 0..255 (cols k0..k0+63)
            const u16* kbase = QK + (size_t)(b * 512 + k0) * 2048 + 1024 + h * 256;
            const int r2 = lane >> 5, c = lane & 31;
#pragma unroll
            for (int i = 0; i < 8; ++i) {
                const int rr = w * 16 + i * 2 + r2;
                stage16(kbase + (size_t)rr * 2048 + ((c ^ (rr & 7)) * 8),
                        &sK[(w * 16 + i * 2) * 256], lane);
            }
            const u16* vbase = Vt + ((size_t)(b * 4 + h) * 256) * 512 + k0;
            const int vr = lane >> 3, vc = lane & 7;
#pragma unroll
            for (int i = 0; i < 8; ++i) {
                const int dd = w * 64 + i * 8 + vr;
                stage16(vbase + (size_t)dd * 512 + ((vc ^ (dd & 7)) * 8),
                        &sV[(w * 64 + i * 8) * 64], lane);
            }
        }
        __syncthreads();   // staging drained

        // ---- QK^T: S[16q x 64k] per wave ----
        f32x4 sacc[4];
#pragma unroll
        for (int kt4 = 0; kt4 < 4; ++kt4) {
            sacc[kt4][0] = 0.f; sacc[kt4][1] = 0.f;
            sacc[kt4][2] = 0.f; sacc[kt4][3] = 0.f;
        }
#pragma unroll
        for (int ds = 0; ds < 8; ++ds) {
            const int chunk = ds * 4 + quad;
#pragma unroll
            for (int kt4 = 0; kt4 < 4; ++kt4) {
                const int kr = kt4 * 16 + row;
                const short8 kf = *(const short8*)&sK[kr * 256 + ((chunk ^ (kr & 7)) * 8)];
                sacc[kt4] = __builtin_amdgcn_mfma_f32_16x16x32_bf16(
                    qf[ds], kf, sacc[kt4], 0, 0, 0);
            }
        }

        // ---- online softmax (rows q = w*16 + quad*4 + j, cols k = kt4*16+row)
        const int diag = (kt == qt);
        float sc[4][4];
#pragma unroll
        for (int kt4 = 0; kt4 < 4; ++kt4)
#pragma unroll
            for (int j = 0; j < 4; ++j) {
                float v = sacc[kt4][j] * 0.03125f;     // 1/sqrt(1024)
                if (diag && (kt4 * 16 + row > w * 16 + quad * 4 + j)) v = -3.0e38f;
                sc[kt4][j] = v;
            }
        float alpha[4];
#pragma unroll
        for (int j = 0; j < 4; ++j) {
            float lm = fmaxf(fmaxf(sc[0][j], sc[1][j]), fmaxf(sc[2][j], sc[3][j]));
            lm = fmaxf(lm, __shfl_xor(lm, 1));
            lm = fmaxf(lm, __shfl_xor(lm, 2));
            lm = fmaxf(lm, __shfl_xor(lm, 4));
            lm = fmaxf(lm, __shfl_xor(lm, 8));
            const float mnew = fmaxf(mrow[j], lm);
            alpha[j] = __expf(mrow[j] - mnew);
            float ps = 0.f;
#pragma unroll
            for (int kt4 = 0; kt4 < 4; ++kt4) {
                sc[kt4][j] = __expf(sc[kt4][j] - mnew);
                ps += sc[kt4][j];
            }
            ps += __shfl_xor(ps, 1);
            ps += __shfl_xor(ps, 2);
            ps += __shfl_xor(ps, 4);
            ps += __shfl_xor(ps, 8);
            lrow[j] = lrow[j] * alpha[j] + ps;
            mrow[j] = mnew;
        }
        // P -> bf16 wave-private LDS (swizzled rows)
#pragma unroll
        for (int kt4 = 0; kt4 < 4; ++kt4)
#pragma unroll
            for (int j = 0; j < 4; ++j) {
                const int ql = quad * 4 + j;
                const int k = kt4 * 16 + row;
                sP[w][ql * 64 + (((k >> 3) ^ (ql & 7)) * 8) + (k & 7)] = f2bf(sc[kt4][j]);
            }
        // rescale O accumulators
#pragma unroll
        for (int dt = 0; dt < 16; ++dt) {
            oacc[dt][0] *= alpha[0]; oacc[dt][1] *= alpha[1];
            oacc[dt][2] *= alpha[2]; oacc[dt][3] *= alpha[3];
        }
        // ---- PV: O[16q x 256d] += P[16q x 64k] * Vt[256d x 64k]^T ----
#pragma unroll
        for (int kk = 0; kk < 2; ++kk) {
            const int chunk = kk * 4 + quad;
            const short8 pf = *(const short8*)&sP[w][row * 64 + ((chunk ^ (row & 7)) * 8)];
#pragma unroll
            for (int dt = 0; dt < 16; ++dt) {
                const int dr = dt * 16 + row;
                const short8 vf = *(const short8*)&sV[dr * 64 + ((chunk ^ (dr & 7)) * 8)];
                oacc[dt] = __builtin_amdgcn_mfma_f32_16x16x32_bf16(
                    pf, vf, oacc[dt], 0, 0, 0);
            }
        }
        __syncthreads();   // LDS reads done before next-tile staging
    }

    // ---- epilogue: faithful [B,HEADS,S,dh] flat order, zero invalid rows
    const int len = lengths[b];
#pragma unroll
    for (int j = 0; j < 4; ++j) {
        const int qg = q0 + w * 16 + quad * 4 + j;
        const float linv = (qg < len) ? 1.f / lrow[j] : 0.f;
        float* op = O + ((size_t)((b * 4 + h) * 512 + qg)) * 256;
#pragma unroll
        for (int dt = 0; dt < 16; ++dt)
            op[dt * 16 + row] = oacc[dt][j] * linv;
        if (atten && row == 0)
            atten[(size_t)(b * 4 + h) * 512 + qg] = linv;   // max_k p = 1/l
    }
}

// ---------------------------------------------------------------------------
// Embedding + sinusoidal PE, dual fp32/bf16 output
// ---------------------------------------------------------------------------
__global__ __launch_bounds__(256) void embed_kernel(
    const int* __restrict__ x, const float* __restrict__ emb,
    float* __restrict__ Z, u16* __restrict__ Zb)
{
    const int tokidx = blockIdx.x;
    const int s = tokidx & 511;
    const int t = threadIdx.x;
    const int tok = x[tokidx];
    const int c0 = t << 2;
    float4 e = *(const float4*)(emb + (size_t)tok * 1024 + c0);
    float pe[4];
#pragma unroll
    for (int j = 0; j < 4; ++j) {
        int c = c0 + j;
        float freq = expf((float)(c & ~1) * (-9.210340371976184f / 1024.f));
        float arg = (float)s * freq;
        pe[j] = (c & 1) ? cosf(arg) : sinf(arg);
    }
    float4 o = make_float4(e.x + pe[0], e.y + pe[1], e.z + pe[2], e.w + pe[3]);
    *(float4*)(Z + (size_t)tokidx * 1024 + c0) = o;
    ushort4 ob = {f2bf(o.x), f2bf(o.y), f2bf(o.z), f2bf(o.w)};
    ((ushort4*)(Zb + (size_t)tokidx * 1024))[t] = ob;
}

// ---------------------------------------------------------------------------
// Y = LayerNorm(X + R) * g + be, dual fp32/bf16 output (H = 1024)
// ---------------------------------------------------------------------------
__global__ __launch_bounds__(256) void add_ln(
    const float* __restrict__ X, const float* __restrict__ R,
    const float* __restrict__ g, const float* __restrict__ be,
    float* __restrict__ Y, u16* __restrict__ Yb)
{
    __shared__ float red[8];
    const int row = blockIdx.x;
    const int t = threadIdx.x;
    const float4 x = ((const float4*)(X + (size_t)row * 1024))[t];
    const float4 r = ((const float4*)(R + (size_t)row * 1024))[t];
    float v[4] = {x.x + r.x, x.y + r.y, x.z + r.z, x.w + r.w};
    float s = v[0] + v[1] + v[2] + v[3];
#pragma unroll
    for (int off = 32; off; off >>= 1) s += __shfl_xor(s, off);
    const int wid = t >> 6;
    if ((t & 63) == 0) red[wid] = s;
    __syncthreads();
    s = red[0] + red[1] + red[2] + red[3];
    const float mean = s * (1.f / 1024.f);
    float q = 0.f;
#pragma unroll
    for (int j = 0; j < 4; ++j) { float d = v[j] - mean; q += d * d; }
#pragma unroll
    for (int off = 32; off; off >>= 1) q += __shfl_xor(q, off);
    if ((t & 63) == 0) red[4 + wid] = q;
    __syncthreads();
    q = red[4] + red[5] + red[6] + red[7];
    const float rstd = rsqrtf(q * (1.f / 1024.f) + 1e-5f);
    const float4 gv = ((const float4*)g)[t];
    const float4 bv = ((const float4*)be)[t];
    float4 o;
    o.x = (v[0] - mean) * rstd * gv.x + bv.x;
    o.y = (v[1] - mean) * rstd * gv.y + bv.y;
    o.z = (v[2] - mean) * rstd * gv.z + bv.z;
    o.w = (v[3] - mean) * rstd * gv.w + bv.w;
    ((float4*)(Y + (size_t)row * 1024))[t] = o;
    ushort4 ob = {f2bf(o.x), f2bf(o.y), f2bf(o.z), f2bf(o.w)};
    ((ushort4*)(Yb + (size_t)row * 1024))[t] = ob;
}

// ---------------------------------------------------------------------------
// In-place row softmax over V=8000
// ---------------------------------------------------------------------------
__global__ __launch_bounds__(256) void softmax8000(float* __restrict__ P)
{
    __shared__ float red[8];
    float* p = P + (size_t)blockIdx.x * 8000;
    const int t = threadIdx.x;
    float vals[32];
    float mx = -3.0e38f;
#pragma unroll
    for (int j = 0; j < 32; ++j) {
        int c = t + (j << 8);
        if (c < 8000) { vals[j] = p[c]; mx = fmaxf(mx, vals[j]); }
    }
#pragma unroll
    for (int off = 32; off; off >>= 1) mx = fmaxf(mx, __shfl_xor(mx, off));
    const int wid = t >> 6;
    if ((t & 63) == 0) red[wid] = mx;
    __syncthreads();
    mx = fmaxf(fmaxf(red[0], red[1]), fmaxf(red[2], red[3]));
    float sum = 0.f;
#pragma unroll
    for (int j = 0; j < 32; ++j) {
        int c = t + (j << 8);
        if (c < 8000) { vals[j] = expf(vals[j] - mx); sum += vals[j]; }
    }
#pragma unroll
    for (int off = 32; off; off >>= 1) sum += __shfl_xor(sum, off);
    if ((t & 63) == 0) red[4 + wid] = sum;
    __syncthreads();
    const float inv = 1.f / (red[4] + red[5] + red[6] + red[7]);
#pragma unroll
    for (int j = 0; j < 32; ++j) {
        int c = t + (j << 8);
        if (c < 8000) p[c] = vals[j] * inv;
    }
}

// ---------------------------------------------------------------------------
// Weight / embedding conversion kernels (fp32 -> bf16), run each call
// ---------------------------------------------------------------------------
__global__ __launch_bounds__(256) void cvt_qkv(
    const float* __restrict__ Wq, const float* __restrict__ Wk,
    const float* __restrict__ Wv, u16* __restrict__ dst)
{
    const int n = blockIdx.x, l = blockIdx.y, t = threadIdx.x;
    const float* src = (n < 1024) ? Wq + ((size_t)l * 1024 + n) * 1024
                     : (n < 2048) ? Wk + ((size_t)l * 1024 + (n - 1024)) * 1024
                                  : Wv + ((size_t)l * 1024 + (n - 2048)) * 1024;
    float4 v = ((const float4*)src)[t];
    ushort4 o = {f2bf(v.x), f2bf(v.y), f2bf(v.z), f2bf(v.w)};
    ((ushort4*)(dst + ((size_t)l * 3072 + n) * 1024))[t] = o;
}

__global__ __launch_bounds__(256) void cvt_bias_qkv(
    const float* __restrict__ bq, const float* __restrict__ bk,
    const float* __restrict__ bv, float* __restrict__ dst)
{
    const int i = blockIdx.x * 256 + threadIdx.x;
    if (i >= 8 * 3072) return;
    const int l = i / 3072, n = i - l * 3072;
    float v = (n < 1024) ? bq[l * 1024 + n]
            : (n < 2048) ? bk[l * 1024 + (n - 1024)]
                         : bv[l * 1024 + (n - 2048)];
    dst[i] = v;
}

__global__ __launch_bounds__(256) void cvt_plain(
    const float* __restrict__ src, u16* __restrict__ dst, int n)
{
    const int i = (blockIdx.x * 256 + threadIdx.x) * 4;
    if (i >= n) return;
    float4 v = *(const float4*)(src + i);
    ushort4 o = {f2bf(v.x), f2bf(v.y), f2bf(v.z), f2bf(v.w)};
    *(ushort4*)(dst + i) = o;
}

__global__ __launch_bounds__(256) void cvt_emb(
    const float* __restrict__ emb, u16* __restrict__ dst)
{
    const int r = blockIdx.x, t = threadIdx.x;   // 8064 rows (pad to tile)
    ushort4 o = {0, 0, 0, 0};
    if (r < 8000) {
        float4 v = ((const float4*)(emb + (size_t)r * 1024))[t];
        o.x = f2bf(v.x); o.y = f2bf(v.y); o.z = f2bf(v.z); o.w = f2bf(v.w);
    }
    ((ushort4*)(dst + (size_t)r * 1024))[t] = o;
}

// ---------------------------------------------------------------------------
extern "C" void kernel_launch(void* const* d_in, const int* in_sizes, int n_in,
                              void* d_out, int out_size, void* d_ws, size_t ws_size,
                              hipStream_t stream)
{
    (void)in_sizes; (void)n_in; (void)out_size;
    const int*   x       = (const int*)d_in[0];
    const int*   lengths = (const int*)d_in[1];
    const float* emb = (const float*)d_in[2];
    const float* Wq  = (const float*)d_in[3];
    const float* bq  = (const float*)d_in[4];
    const float* Wk  = (const float*)d_in[5];
    const float* bk  = (const float*)d_in[6];
    const float* Wv  = (const float*)d_in[7];
    const float* bv  = (const float*)d_in[8];
    const float* W1  = (const float*)d_in[9];
    const float* b1  = (const float*)d_in[10];
    const float* W2  = (const float*)d_in[11];
    const float* b2  = (const float*)d_in[12];
    const float* g1  = (const float*)d_in[13];
    const float* be1 = (const float*)d_in[14];
    const float* g2  = (const float*)d_in[15];
    const float* be2 = (const float*)d_in[16];
    const float* Wfc = (const float*)d_in[17];
    const float* bfc = (const float*)d_in[18];

    float* out = (float*)d_out;
    float* atten = out + (size_t)65536000;

    // ---- buffer sizes (bytes, all 256-aligned already) ----
    const size_t SZ_EMBB = (size_t)8064 * 1024 * 2;   // padded emb bf16
    const size_t SZ_FCB  = (size_t)8192 * 1024 * 2;   // out_fc bf16 (survives to logits)
    const size_t SZ_BQKV = (size_t)8 * 3072 * 4;
    const size_t SZ_WQKV = (size_t)8 * 3072 * 1024 * 2;
    const size_t SZ_W12  = (size_t)8 * 1024 * 1024 * 2;
    const size_t SZ_WFC  = (size_t)1024 * 1024 * 2;
    const size_t SZ_Z    = (size_t)8192 * 1024 * 4;
    const size_t SZ_ZB   = (size_t)8192 * 1024 * 2;
    const size_t SZ_QKB  = (size_t)8192 * 2048 * 2;   // Q,K only
    const size_t SZ_VT   = (size_t)16 * 4 * 256 * 512 * 2;  // V transposed
    const size_t NONFORCED = SZ_WQKV + 2 * SZ_W12 + SZ_WFC + 2 * SZ_Z + SZ_ZB
                           + SZ_QKB + SZ_VT + SZ_Z;
    const size_t FORCED = SZ_EMBB + SZ_FCB + SZ_BQKV;
    const size_t GRAND = FORCED + NONFORCED;

    char* wsc = (char*)d_ws;
    char* oc  = (char*)d_out;
    const size_t ocap = (size_t)65536000 * 4;   // y_prim region: dead until logits GEMM
    size_t wo = 0, oo = 0;
    const bool all_ws = ws_size >= GRAND;
    // forced-to-ws (must survive while logits GEMM overwrites d_out):
    u16*   emb_bf = (u16*)(wsc + wo);  wo += SZ_EMBB;
    u16*   fc_b   = (u16*)(wsc + wo);  wo += SZ_FCB;
    float* bqkv   = (float*)(wsc + wo); wo += SZ_BQKV;
    auto alloc = [&](size_t sz) -> char* {
        if (all_ws) { char* p = wsc + wo; wo += sz; return p; }
        if (oo + sz <= ocap) { char* p = oc + oo; oo += sz; return p; }
        char* p = wsc + wo; wo += sz; return p;
    };
    u16*   Wqkv_bf = (u16*)alloc(SZ_WQKV);
    u16*   W1b     = (u16*)alloc(SZ_W12);
    u16*   W2b     = (u16*)alloc(SZ_W12);
    u16*   Wfcb    = (u16*)alloc(SZ_WFC);
    float* z       = (float*)alloc(SZ_Z);
    float* z1      = (float*)alloc(SZ_Z);
    u16*   zb      = (u16*)alloc(SZ_ZB);
    u16*   qkb     = (u16*)alloc(SZ_QKB);
    u16*   vtb     = (u16*)alloc(SZ_VT);
    float* o       = (float*)alloc(SZ_Z);
    // aliases inside qkb (attention finishes before these are written):
    u16* z1b = qkb;                             // [8192][1024] bf16
    u16* f1b = qkb + (size_t)8192 * 1024;       // [8192][1024] bf16

    dim3 blk(256);
    // weight / emb conversion (reads pristine fp32 inputs every call)
    cvt_qkv<<<dim3(3072, 8), blk, 0, stream>>>(Wq, Wk, Wv, Wqkv_bf);
    cvt_bias_qkv<<<96, blk, 0, stream>>>(bq, bk, bv, bqkv);
    cvt_plain<<<8192, blk, 0, stream>>>(W1, W1b, 8 * 1024 * 1024);
    cvt_plain<<<8192, blk, 0, stream>>>(W2, W2b, 8 * 1024 * 1024);
    cvt_plain<<<1024, blk, 0, stream>>>(Wfc, Wfcb, 1024 * 1024);
    cvt_emb<<<8064, blk, 0, stream>>>(emb, emb_bf);

    embed_kernel<<<8192, blk, 0, stream>>>(x, emb, z, zb);

    for (int l = 0; l < 8; ++l) {
        const size_t WO1 = (size_t)l * 1024 * 1024;
        const size_t BO = (size_t)l * 1024;
        // fused QKV GEMM (pipelined): Q,K bf16 -> qkb (ldc 2048), V^T -> vtb
        gemm_p<<<dim3(24, 64), blk, 0, stream>>>(
            zb, Wqkv_bf + (size_t)l * 3072 * 1024, bqkv + (size_t)l * 3072,
            qkb, 8192, 3072, 1024, 2048, 3072, 1 | 4, vtb);
        attn_mfma<<<dim3(8, 4, 16), blk, 0, stream>>>(
            qkb, vtb, lengths, o, (l == 7) ? atten : nullptr);
        add_ln<<<8192, blk, 0, stream>>>(z, o, g1 + BO, be1 + BO, z1, z1b);
        gemm_p<<<dim3(8, 64), blk, 0, stream>>>(
            z1b, W1b + WO1, b1 + BO, f1b, 8192, 1024, 1024, 1024, 1024, 1 | 2, nullptr);
        gemm_p<<<dim3(8, 64), blk, 0, stream>>>(
            f1b, W2b + WO1, b2 + BO, o, 8192, 1024, 1024, 1024, 1024, 0, nullptr);
        add_ln<<<8192, blk, 0, stream>>>(z1, o, g2 + BO, be2 + BO, z, zb);
    }
    gemm_p<<<dim3(8, 64), blk, 0, stream>>>(
        zb, Wfcb, bfc, fc_b, 8192, 1024, 1024, 1024, 1024, 1, nullptr);
    // logits GEMM (pipelined, emb padded to 8064 rows)
    gemm_p<<<dim3(63, 64), blk, 0, stream>>>(
        fc_b, emb_bf, nullptr, out, 8192, 8064, 1024, 8000, 8000, 0, nullptr);
    softmax8000<<<8192, blk, 0, stream>>>(out);
}